// Round 1
// baseline (158278.333 us; speedup 1.0000x reference)
//
#include <hip/hip_runtime.h>

#define N_B 128
#define LSEQ 2048
#define HID 512

// ws layout (float offsets)
#define OFF_YT 0
#define OFF_H1 (LSEQ*N_B)                // yT: 262144 floats
#define OFF_H2 (OFF_H1 + 2*HID*N_B)     // h1 double buffer: 131072
#define OFF_SYNC (OFF_H2 + 2*HID*N_B)   // h2 double buffer: 131072

#define NBLK 194

__device__ __forceinline__ float sigm(float x){ return 1.0f/(1.0f + __expf(-x)); }
__device__ __forceinline__ float tanhf_fast(float x){
  float ax = fabsf(x);
  float e = __expf(2.0f*ax);
  float t = 1.0f - 2.0f/(e + 1.0f);   // overflow-safe: e=inf -> t=1
  return x < 0.0f ? -t : t;
}

// transpose y -> yT[t][n]; zero h1buf[1], h2buf[1]; reset barrier counters.
// Runs every launch so graph replays are deterministic.
__global__ void init_kernel(const float* __restrict__ y, float* __restrict__ ws){
  int idx = blockIdx.x*256 + threadIdx.x;
  if (idx < LSEQ*N_B){
    int t = idx >> 7, n = idx & 127;
    ws[OFF_YT + idx] = y[n*LSEQ + t];
  }
  if (idx < HID*N_B){
    ws[OFF_H1 + HID*N_B + idx] = 0.0f;
    ws[OFF_H2 + HID*N_B + idx] = 0.0f;
  }
  if (idx < 2){
    ((unsigned*)(ws + OFF_SYNC))[idx] = 0u;
  }
}

__device__ __forceinline__ void grid_barrier(unsigned* cnt, unsigned* gen,
                                             unsigned nblk, unsigned& mygen){
  __syncthreads();   // compiler drains each wave's vmcnt before s_barrier
  if (threadIdx.x == 0){
    unsigned arrived = __hip_atomic_fetch_add(cnt, 1u, __ATOMIC_ACQ_REL, __HIP_MEMORY_SCOPE_AGENT);
    if (arrived == nblk - 1u){
      __hip_atomic_store(cnt, 0u, __ATOMIC_RELAXED, __HIP_MEMORY_SCOPE_AGENT);
      __hip_atomic_fetch_add(gen, 1u, __ATOMIC_RELEASE, __HIP_MEMORY_SCOPE_AGENT);
    } else {
      while (__hip_atomic_load(gen, __ATOMIC_RELAXED, __HIP_MEMORY_SCOPE_AGENT) == mygen){
        __builtin_amdgcn_s_sleep(1);
      }
      __builtin_amdgcn_fence(__ATOMIC_ACQUIRE, "agent");
    }
  }
  mygen++;
  __syncthreads();
}

// stage 256 k-rows x 64 batch (64KB) global -> LDS, layout lds[k*64 + n]
__device__ __forceinline__ void stage_chunk(const float* __restrict__ src,
                                            float* __restrict__ ldsp, int tid){
  #pragma unroll
  for (int j = 0; j < 16; ++j){
    int idx4 = tid + j*256;            // float4 index 0..4095
    int k_l  = idx4 >> 4;              // 0..255
    int nl4  = idx4 & 15;              // float4 within 64-float row
    reinterpret_cast<float4*>(ldsp)[idx4] =
        reinterpret_cast<const float4*>(src + k_l*N_B)[nl4];
  }
}

__launch_bounds__(256)
__global__ void lstm_kernel(
    const float* __restrict__ yT,
    const float* __restrict__ Wih1, const float* __restrict__ Whh1,
    const float* __restrict__ bi1,  const float* __restrict__ bh1,
    const float* __restrict__ Wih2, const float* __restrict__ Whh2,
    const float* __restrict__ bi2,  const float* __restrict__ bh2,
    const float* __restrict__ Wlin, const float* __restrict__ blin,
    float* __restrict__ h1b, float* __restrict__ h2b,
    float* __restrict__ out, unsigned* __restrict__ syncp)
{
  __shared__ float lds[64*256];   // 64KB
  const int tid  = threadIdx.x;
  const int lane = tid & 63;
  const int wv   = __builtin_amdgcn_readfirstlane(tid >> 6);
  const int blk  = blockIdx.x;
  unsigned* cnt = syncp;
  unsigned* gen = syncp + 1;
  unsigned mygen = 0;

  if (blk < 64){
    // ---- layer-1 blocks: 2 batch-groups x 32 unit-groups (16 units each) ----
    const int bg = blk >> 5;
    const int ug = blk & 31;
    const int n0 = bg*64;
    const int u0 = ug*16 + wv*4;          // this wave: 4 units
    int rofs[16]; float bsum[16]; float wih[16];
    #pragma unroll
    for (int u = 0; u < 4; ++u){
      #pragma unroll
      for (int g = 0; g < 4; ++g){
        int row = g*HID + u0 + u;         // gate order i,f,g,o
        rofs[u*4+g] = row*HID;
        bsum[u*4+g] = bi1[row] + bh1[row];
        wih[u*4+g]  = Wih1[row];
      }
    }
    float c1[4] = {0.f,0.f,0.f,0.f};
    for (int p = 0; p < LSEQ + 2; ++p){
      if (p < LSEQ){
        const int pc = p & 1;
        const float* hsrc = h1b + (pc^1)*HID*N_B;   // h1(p-1)
        float acc[16];
        #pragma unroll
        for (int r = 0; r < 16; ++r) acc[r] = 0.f;
        #pragma unroll
        for (int ch = 0; ch < 2; ++ch){
          stage_chunk(hsrc + ch*256*N_B + n0, lds, tid);
          __syncthreads();
          const int kbase = ch*256;
          for (int k4 = 0; k4 < 256; k4 += 4){
            float h0v = lds[(k4+0)*64 + lane];
            float h1v = lds[(k4+1)*64 + lane];
            float h2v = lds[(k4+2)*64 + lane];
            float h3v = lds[(k4+3)*64 + lane];
            const int kg = kbase + k4;
            #pragma unroll
            for (int r = 0; r < 16; ++r){
              const float4 w4 = *reinterpret_cast<const float4*>(Whh1 + rofs[r] + kg);
              acc[r] = fmaf(w4.x, h0v, acc[r]);
              acc[r] = fmaf(w4.y, h1v, acc[r]);
              acc[r] = fmaf(w4.z, h2v, acc[r]);
              acc[r] = fmaf(w4.w, h3v, acc[r]);
            }
          }
          __syncthreads();
        }
        const float yv = yT[p*N_B + n0 + lane];
        float* hdst = h1b + pc*HID*N_B;             // h1(p)
        #pragma unroll
        for (int u = 0; u < 4; ++u){
          float gi = acc[u*4+0] + bsum[u*4+0] + wih[u*4+0]*yv;
          float gf = acc[u*4+1] + bsum[u*4+1] + wih[u*4+1]*yv;
          float gg = acc[u*4+2] + bsum[u*4+2] + wih[u*4+2]*yv;
          float go = acc[u*4+3] + bsum[u*4+3] + wih[u*4+3]*yv;
          float cn = sigm(gf)*c1[u] + sigm(gi)*tanhf_fast(gg);
          c1[u] = cn;
          float hn = sigm(go)*tanhf_fast(cn);
          hdst[(u0+u)*N_B + n0 + lane] = hn;
        }
      }
      grid_barrier(cnt, gen, NBLK, mygen);
    }
  } else if (blk < 192){
    // ---- layer-2 blocks: 2 batch-groups x 64 unit-groups (8 units each) ----
    const int b2 = blk - 64;
    const int bg = b2 >> 6;
    const int ug = b2 & 63;
    const int n0 = bg*64;
    const int u0 = ug*8 + wv*2;           // this wave: 2 units
    int rofs[8]; float bsum[8];
    #pragma unroll
    for (int u = 0; u < 2; ++u){
      #pragma unroll
      for (int g = 0; g < 4; ++g){
        int row = g*HID + u0 + u;
        rofs[u*4+g] = row*HID;
        bsum[u*4+g] = bi2[row] + bh2[row];
      }
    }
    float c2[2] = {0.f, 0.f};
    for (int p = 0; p < LSEQ + 2; ++p){
      if (p >= 1 && p <= LSEQ){
        const int pc = p & 1;
        float acc[8];
        #pragma unroll
        for (int r = 0; r < 8; ++r) acc[r] = 0.f;
        // mv 0: W_ih2 . h1(p-1) from h1b[pc^1];  mv 1: W_hh2 . h2(p-2) from h2b[pc]
        #pragma unroll
        for (int mv = 0; mv < 2; ++mv){
          const float* hsrc = (mv == 0) ? (h1b + (pc^1)*HID*N_B) : (h2b + pc*HID*N_B);
          const float* Wm   = (mv == 0) ? Wih2 : Whh2;
          #pragma unroll
          for (int ch = 0; ch < 2; ++ch){
            stage_chunk(hsrc + ch*256*N_B + n0, lds, tid);
            __syncthreads();
            const int kbase = ch*256;
            for (int k4 = 0; k4 < 256; k4 += 4){
              float h0v = lds[(k4+0)*64 + lane];
              float h1v = lds[(k4+1)*64 + lane];
              float h2v = lds[(k4+2)*64 + lane];
              float h3v = lds[(k4+3)*64 + lane];
              const int kg = kbase + k4;
              #pragma unroll
              for (int r = 0; r < 8; ++r){
                const float4 w4 = *reinterpret_cast<const float4*>(Wm + rofs[r] + kg);
                acc[r] = fmaf(w4.x, h0v, acc[r]);
                acc[r] = fmaf(w4.y, h1v, acc[r]);
                acc[r] = fmaf(w4.z, h2v, acc[r]);
                acc[r] = fmaf(w4.w, h3v, acc[r]);
              }
            }
            __syncthreads();
          }
        }
        float* hdst = h2b + (pc^1)*HID*N_B;         // h2(p-1)
        #pragma unroll
        for (int u = 0; u < 2; ++u){
          float gi = acc[u*4+0] + bsum[u*4+0];
          float gf = acc[u*4+1] + bsum[u*4+1];
          float gg = acc[u*4+2] + bsum[u*4+2];
          float go = acc[u*4+3] + bsum[u*4+3];
          float cn = sigm(gf)*c2[u] + sigm(gi)*tanhf_fast(gg);
          c2[u] = cn;
          float hn = sigm(go)*tanhf_fast(cn);
          hdst[(u0+u)*N_B + n0 + lane] = hn;
        }
      }
      grid_barrier(cnt, gen, NBLK, mygen);
    }
  } else {
    // ---- output blocks: blk 192,193 -> out(t=p-2) = h2(t) . W_lin + b ----
    const int n0 = (blk - 192)*64;
    const float bl = blin[0];
    for (int p = 0; p < LSEQ + 2; ++p){
      if (p >= 2){
        const int pc = p & 1;
        const int t = p - 2;
        const float* h2rd = h2b + pc*HID*N_B + n0;  // h2(p-2)
        float a = 0.f;
        const int kb = wv*128;
        for (int k4 = 0; k4 < 128; k4 += 4){
          const float4 w4 = *reinterpret_cast<const float4*>(Wlin + kb + k4);
          a = fmaf(w4.x, h2rd[(kb+k4+0)*N_B + lane], a);
          a = fmaf(w4.y, h2rd[(kb+k4+1)*N_B + lane], a);
          a = fmaf(w4.z, h2rd[(kb+k4+2)*N_B + lane], a);
          a = fmaf(w4.w, h2rd[(kb+k4+3)*N_B + lane], a);
        }
        lds[wv*64 + lane] = a;
        __syncthreads();
        if (wv == 0){
          float s = lds[lane] + lds[64+lane] + lds[128+lane] + lds[192+lane] + bl;
          out[(n0+lane)*LSEQ + t] = s;
        }
        __syncthreads();
      }
      grid_barrier(cnt, gen, NBLK, mygen);
    }
  }
}

extern "C" void kernel_launch(void* const* d_in, const int* in_sizes, int n_in,
                              void* d_out, int out_size, void* d_ws, size_t ws_size,
                              hipStream_t stream){
  (void)in_sizes; (void)n_in; (void)out_size; (void)ws_size;
  const float* y    = (const float*)d_in[0];
  const float* Wih1 = (const float*)d_in[1];
  const float* Whh1 = (const float*)d_in[2];
  const float* bi1  = (const float*)d_in[3];
  const float* bh1  = (const float*)d_in[4];
  const float* Wih2 = (const float*)d_in[5];
  const float* Whh2 = (const float*)d_in[6];
  const float* bi2  = (const float*)d_in[7];
  const float* bh2  = (const float*)d_in[8];
  const float* Wlin = (const float*)d_in[9];
  const float* blin = (const float*)d_in[10];
  float* ws  = (float*)d_ws;
  float* out = (float*)d_out;

  hipLaunchKernelGGL(init_kernel, dim3((LSEQ*N_B + 255)/256), dim3(256), 0, stream, y, ws);

  const float* yT = ws + OFF_YT;
  float* h1b = ws + OFF_H1;
  float* h2b = ws + OFF_H2;
  unsigned* syncp = (unsigned*)(ws + OFF_SYNC);

  void* args[] = { (void*)&yT, (void*)&Wih1, (void*)&Whh1, (void*)&bi1, (void*)&bh1,
                   (void*)&Wih2, (void*)&Whh2, (void*)&bi2, (void*)&bh2,
                   (void*)&Wlin, (void*)&blin, (void*)&h1b, (void*)&h2b,
                   (void*)&out, (void*)&syncp };
  hipLaunchCooperativeKernel((void*)lstm_kernel, dim3(NBLK), dim3(256), args, 0, stream);
}

// Round 2
// 35318.137 us; speedup vs baseline: 4.4815x; 4.4815x over previous
//
#include <hip/hip_runtime.h>

#define N_B 128
#define LSEQ 2048
#define HID 512

// ws float offsets
#define OFF_YT 0
#define OFF_H1F 262144                 // h1 planes: u16[262144] (=131072 floats)
#define OFF_H2F (OFF_H1F + 131072)
#define OFF_SYNCF (OFF_H2F + 131072)

#define NBLK 98
#define NBLK_BG 49
#define PSUM_OFF 131072                // LDS byte offset of psum area

typedef __attribute__((ext_vector_type(8))) short short8;
typedef __attribute__((ext_vector_type(4))) float f32x4;
typedef __attribute__((ext_vector_type(8))) unsigned short ushort8;

typedef __attribute__((address_space(1))) const unsigned int GU32;
typedef __attribute__((address_space(3))) unsigned int LU32;

__device__ __forceinline__ float sigm(float x){ return 1.0f/(1.0f + __expf(-x)); }
__device__ __forceinline__ float tanhf_fast(float x){
  float ax = fabsf(x);
  float e = __expf(2.0f*ax);
  float t = 1.0f - 2.0f/(e + 1.0f);   // overflow-safe
  return x < 0.0f ? -t : t;
}

__device__ __forceinline__ unsigned short f2bf(float x){    // RNE fp32->bf16
  unsigned u = __builtin_bit_cast(unsigned, x);
  u += 0x7fffu + ((u>>16)&1u);
  return (unsigned short)(u>>16);
}
__device__ __forceinline__ float bf2f(unsigned short h){
  unsigned u = ((unsigned)h)<<16;
  return __builtin_bit_cast(float, u);
}

__device__ __forceinline__ f32x4 mm(short8 a, short8 b, f32x4 c){
  return __builtin_amdgcn_mfma_f32_16x16x32_bf16(a, b, c, 0, 0, 0);
}

// async stage 131072 bytes global->LDS, linear layout, 512 threads
__device__ __forceinline__ void stage_lds(const void* g, unsigned char* smem, int tid){
  const char* gp = (const char*)g;
  #pragma unroll
  for (int i = 0; i < 16; ++i){
    unsigned o = (unsigned)i*8192u + (unsigned)tid*16u;
    __builtin_amdgcn_global_load_lds(
        (GU32*)(gp + o),
        (LU32*)(smem + (unsigned)i*8192u + (unsigned)(tid & ~63)*16u),
        16, 0, 0);
  }
}

// pack 16 A-fragments (hi & lo bf16) for one wave: rows m=ui*4+g -> W[(m&3)*HID + u_w + (m>>2)][k]
__device__ __forceinline__ void apack(const float* __restrict__ W, int u_w, int l15, int hig,
                                      short8* whi, short8* wlo){
  const int m = l15;
  const int row = (m&3)*HID + u_w + (m>>2);
  const float* wp0 = W + row*HID + hig*8;
  #pragma unroll
  for (int kt = 0; kt < 16; ++kt){
    short8 h8, l8;
    #pragma unroll
    for (int j = 0; j < 8; ++j){
      float v = wp0[kt*32 + j];
      unsigned short hb = f2bf(v);
      h8[j] = (short)hb;
      l8[j] = (short)f2bf(v - bf2f(hb));
    }
    whi[kt] = h8; wlo[kt] = l8;
  }
}

__device__ __forceinline__ void ktloop(const unsigned char* smem, const short8* whi, const short8* wlo,
                                       int hig, int l15, f32x4* acc){
  #pragma unroll
  for (int kt = 0; kt < 16; ++kt){
    const unsigned base = (unsigned)((kt*4+hig)*64)*16u;
    #pragma unroll
    for (int nt = 0; nt < 4; ++nt){
      const unsigned eb = base + (unsigned)(nt*16 + l15)*16u;
      short8 bhi = *(const short8*)(smem + eb);
      short8 blo = *(const short8*)(smem + 65536u + eb);
      acc[nt] = mm(whi[kt], bhi, acc[nt]);
      acc[nt] = mm(wlo[kt], bhi, acc[nt]);
      acc[nt] = mm(whi[kt], blo, acc[nt]);
    }
  }
}

__device__ __forceinline__ void grid_barrier(unsigned* cnt, unsigned* gen,
                                             unsigned nblk, unsigned& mygen){
  __syncthreads();
  if (threadIdx.x == 0){
    unsigned arrived = __hip_atomic_fetch_add(cnt, 1u, __ATOMIC_ACQ_REL, __HIP_MEMORY_SCOPE_AGENT);
    if (arrived == nblk - 1u){
      __hip_atomic_store(cnt, 0u, __ATOMIC_RELAXED, __HIP_MEMORY_SCOPE_AGENT);
      __hip_atomic_fetch_add(gen, 1u, __ATOMIC_RELEASE, __HIP_MEMORY_SCOPE_AGENT);
    } else {
      while (__hip_atomic_load(gen, __ATOMIC_RELAXED, __HIP_MEMORY_SCOPE_AGENT) == mygen){
        __builtin_amdgcn_s_sleep(1);
      }
      __builtin_amdgcn_fence(__ATOMIC_ACQUIRE, "agent");
    }
  }
  mygen++;
  __syncthreads();
}

// transpose y -> yT; zero "previous" h plane buffers (buf 1) and sync words
__global__ void init_kernel(const float* __restrict__ y, float* __restrict__ ws){
  int idx = blockIdx.x*256 + threadIdx.x;
  if (idx < LSEQ*N_B){
    int t = idx >> 7, n = idx & 127;
    ws[OFF_YT + idx] = y[n*LSEQ + t];
  }
  if (idx < 65536){
    ((unsigned*)(ws + OFF_H1F))[65536 + idx] = 0u;
    ((unsigned*)(ws + OFF_H2F))[65536 + idx] = 0u;
  }
  if (idx < 4) ((unsigned*)(ws + OFF_SYNCF))[idx] = 0u;
}

__launch_bounds__(512)
__global__ void lstm_kernel(
    const float* __restrict__ yT,
    const float* __restrict__ Wih1, const float* __restrict__ Whh1,
    const float* __restrict__ bi1,  const float* __restrict__ bh1,
    const float* __restrict__ Wih2, const float* __restrict__ Whh2,
    const float* __restrict__ bi2,  const float* __restrict__ bh2,
    const float* __restrict__ Wlin, const float* __restrict__ blin,
    unsigned short* __restrict__ h1u, unsigned short* __restrict__ h2u,
    float* __restrict__ out, unsigned* __restrict__ syncp)
{
  __shared__ unsigned char smem[147456];   // 128KB stage + 16KB psum
  const int tid  = threadIdx.x;
  const int lane = tid & 63;
  const int wv   = __builtin_amdgcn_readfirstlane(tid >> 6);
  const int blk  = blockIdx.x;
  const int l15  = lane & 15, hig = lane >> 4;
  unsigned mygen = 0;

  if (blk < 32){
    // -------- layer 1: 2bg x 16 blocks, 32 units/block, wave = 4 units --------
    const int bg = blk >> 4, ug = blk & 15;
    const int u_w = ug*32 + wv*4;
    unsigned* cnt = syncp + bg*2; unsigned* gen = cnt + 1;
    short8 whi[16], wlo[16];
    apack(Whh1, u_w, l15, hig, whi, wlo);
    float bsum[4], wih[4];
    #pragma unroll
    for (int r = 0; r < 4; ++r){
      int row = r*HID + u_w + hig;
      bsum[r] = bi1[row] + bh1[row];
      wih[r]  = Wih1[row];
    }
    float c1[4] = {0.f,0.f,0.f,0.f};
    const int u_abs = u_w + hig;
    const int ebase = ((u_abs>>5)*4 + ((u_abs>>3)&3))*512 + (u_abs&7);

    #pragma clang loop unroll(disable)
    for (int p = 0; p < LSEQ + 2; ++p){
      if (p < LSEQ){
        const int pc = p & 1;
        stage_lds(h1u + (((pc^1)*2 + bg) << 16), smem, tid);
        float yv[4];
        #pragma unroll
        for (int nt = 0; nt < 4; ++nt) yv[nt] = yT[p*N_B + bg*64 + nt*16 + l15];
        __syncthreads();
        f32x4 acc[4];
        #pragma unroll
        for (int nt = 0; nt < 4; ++nt) acc[nt] = (f32x4){0.f,0.f,0.f,0.f};
        ktloop(smem, whi, wlo, hig, l15, acc);
        unsigned short* hd = h1u + ((pc*2 + bg) << 16);
        #pragma unroll
        for (int nt = 0; nt < 4; ++nt){
          float gi = acc[nt][0] + bsum[0] + wih[0]*yv[nt];
          float gf = acc[nt][1] + bsum[1] + wih[1]*yv[nt];
          float gg = acc[nt][2] + bsum[2] + wih[2]*yv[nt];
          float go = acc[nt][3] + bsum[3] + wih[3]*yv[nt];
          float cn = sigm(gf)*c1[nt] + sigm(gi)*tanhf_fast(gg);
          c1[nt] = cn;
          float hn = sigm(go)*tanhf_fast(cn);
          unsigned short hb = f2bf(hn);
          unsigned short lb = f2bf(hn - bf2f(hb));
          int e = ebase + (nt*16 + l15)*8;
          hd[e] = hb; hd[32768 + e] = lb;
        }
      }
      grid_barrier(cnt, gen, NBLK_BG, mygen);
    }
  } else if (blk < 96){
    // -------- layer 2: 2bg x 32 blocks, 16 units/block; waves: mt=wv&3, mat=wv>>2 --------
    const int b2 = blk - 32, bg = b2 >> 5, ub = (b2 & 31)*16;
    unsigned* cnt = syncp + bg*2; unsigned* gen = cnt + 1;
    const int mt = wv & 3, mat = wv >> 2;
    const int u_w = ub + mt*4;
    short8 whi[16], wlo[16];
    apack(mat ? Whh2 : Wih2, u_w, l15, hig, whi, wlo);
    float bsum[4], c2[4] = {0.f,0.f,0.f,0.f};
    #pragma unroll
    for (int r = 0; r < 4; ++r){
      int row = r*HID + u_w + hig;
      bsum[r] = bi2[row] + bh2[row];
    }
    const int u_abs = u_w + hig;
    const int ebase = ((u_abs>>5)*4 + ((u_abs>>3)&3))*512 + (u_abs&7);

    #pragma clang loop unroll(disable)
    for (int p = 0; p < LSEQ + 2; ++p){
      if (p >= 1 && p <= LSEQ){
        const int pc = p & 1;
        f32x4 acc[4];
        #pragma unroll
        for (int nt = 0; nt < 4; ++nt) acc[nt] = (f32x4){0.f,0.f,0.f,0.f};
        // phase A: stage h1(p-1), ih-waves compute
        stage_lds(h1u + (((pc^1)*2 + bg) << 16), smem, tid);
        __syncthreads();
        if (mat == 0) ktloop(smem, whi, wlo, hig, l15, acc);
        __syncthreads();
        // phase B: stage h2(p-2), hh-waves compute, dump psum
        stage_lds(h2u + ((pc*2 + bg) << 16), smem, tid);
        __syncthreads();
        if (mat == 1){
          ktloop(smem, whi, wlo, hig, l15, acc);
          #pragma unroll
          for (int nt = 0; nt < 4; ++nt)
            *(f32x4*)(smem + PSUM_OFF + (unsigned)((mt*4+nt)*64 + lane)*16u) = acc[nt];
        }
        __syncthreads();
        if (mat == 0){
          unsigned short* hd = h2u + (((pc^1)*2 + bg) << 16);
          #pragma unroll
          for (int nt = 0; nt < 4; ++nt){
            f32x4 ps = *(const f32x4*)(smem + PSUM_OFF + (unsigned)((mt*4+nt)*64 + lane)*16u);
            float gi = acc[nt][0] + ps[0] + bsum[0];
            float gf = acc[nt][1] + ps[1] + bsum[1];
            float gg = acc[nt][2] + ps[2] + bsum[2];
            float go = acc[nt][3] + ps[3] + bsum[3];
            float cn = sigm(gf)*c2[nt] + sigm(gi)*tanhf_fast(gg);
            c2[nt] = cn;
            float hn = sigm(go)*tanhf_fast(cn);
            unsigned short hb = f2bf(hn);
            unsigned short lb = f2bf(hn - bf2f(hb));
            int e = ebase + (nt*16 + l15)*8;
            hd[e] = hb; hd[32768 + e] = lb;
          }
        }
      }
      grid_barrier(cnt, gen, NBLK_BG, mygen);
    }
  } else {
    // -------- output blocks (one per bg): out(t) = h2(t).Wlin + b --------
    const int bg = blk - 96;
    unsigned* cnt = syncp + bg*2; unsigned* gen = cnt + 1;
    float wl[64];
    #pragma unroll
    for (int g8 = 0; g8 < 8; ++g8){
      int kt = wv*2 + (g8>>2), hg = g8 & 3;
      #pragma unroll
      for (int j = 0; j < 8; ++j) wl[g8*8+j] = Wlin[kt*32 + hg*8 + j];
    }
    const float bl = blin[0];
    #pragma clang loop unroll(disable)
    for (int p = 0; p < LSEQ + 2; ++p){
      if (p >= 2){
        const int pc = p & 1;
        const int t = p - 2;
        const unsigned short* hr = h2u + ((pc*2 + bg) << 16);
        float a = 0.f;
        #pragma unroll
        for (int g8 = 0; g8 < 8; ++g8){
          int kt = wv*2 + (g8>>2), hg = g8 & 3;
          unsigned e = (unsigned)((kt*4+hg)*64 + lane)*8u;
          ushort8 hi8 = *(const ushort8*)(hr + e);
          ushort8 lo8 = *(const ushort8*)(hr + 32768u + e);
          #pragma unroll
          for (int j = 0; j < 8; ++j)
            a += (bf2f(hi8[j]) + bf2f(lo8[j])) * wl[g8*8+j];
        }
        ((float*)smem)[wv*64 + lane] = a;
        __syncthreads();
        if (wv == 0){
          float s = bl;
          #pragma unroll
          for (int w = 0; w < 8; ++w) s += ((float*)smem)[w*64 + lane];
          out[(bg*64 + lane)*LSEQ + t] = s;
        }
        __syncthreads();
      }
      grid_barrier(cnt, gen, NBLK_BG, mygen);
    }
  }
}

extern "C" void kernel_launch(void* const* d_in, const int* in_sizes, int n_in,
                              void* d_out, int out_size, void* d_ws, size_t ws_size,
                              hipStream_t stream){
  (void)in_sizes; (void)n_in; (void)out_size; (void)ws_size;
  const float* y    = (const float*)d_in[0];
  const float* Wih1 = (const float*)d_in[1];
  const float* Whh1 = (const float*)d_in[2];
  const float* bi1  = (const float*)d_in[3];
  const float* bh1  = (const float*)d_in[4];
  const float* Wih2 = (const float*)d_in[5];
  const float* Whh2 = (const float*)d_in[6];
  const float* bi2  = (const float*)d_in[7];
  const float* bh2  = (const float*)d_in[8];
  const float* Wlin = (const float*)d_in[9];
  const float* blin = (const float*)d_in[10];
  float* ws  = (float*)d_ws;
  float* out = (float*)d_out;

  hipLaunchKernelGGL(init_kernel, dim3(1024), dim3(256), 0, stream, y, ws);

  const float* yT = ws + OFF_YT;
  unsigned short* h1u = (unsigned short*)(ws + OFF_H1F);
  unsigned short* h2u = (unsigned short*)(ws + OFF_H2F);
  unsigned* syncp = (unsigned*)(ws + OFF_SYNCF);

  void* args[] = { (void*)&yT, (void*)&Wih1, (void*)&Whh1, (void*)&bi1, (void*)&bh1,
                   (void*)&Wih2, (void*)&Whh2, (void*)&bi2, (void*)&bh2,
                   (void*)&Wlin, (void*)&blin, (void*)&h1u, (void*)&h2u,
                   (void*)&out, (void*)&syncp };
  hipLaunchCooperativeKernel((void*)lstm_kernel, dim3(NBLK), dim3(512), args, 0, stream);
}

// Round 3
// 28707.861 us; speedup vs baseline: 5.5134x; 1.2303x over previous
//
#include <hip/hip_runtime.h>

#define N_B 128
#define LSEQ 2048
#define HID 512

// ws float offsets
#define OFF_YT 0
#define OFF_H1F 262144                 // h1 ring: 4 slots x 2 bg x 65536 u16 = 1MB
#define OFF_H2F (OFF_H1F + 262144)     // h2 ring: 1MB
#define OFF_FLAGS (OFF_H2F + 262144)   // 8*2056 u32 = 64KB
#define FSTRIDE 2056

#define PSUM_OFF 131072                // LDS byte offset of psum area

typedef __attribute__((ext_vector_type(8))) short short8;
typedef __attribute__((ext_vector_type(4))) float f32x4;
typedef __attribute__((ext_vector_type(8))) unsigned short ushort8;

typedef __attribute__((address_space(1))) const unsigned int GU32;
typedef __attribute__((address_space(3))) unsigned int LU32;

__device__ __forceinline__ float sigm(float x){ return 1.0f/(1.0f + __expf(-x)); }
__device__ __forceinline__ float tanhf_fast(float x){
  float ax = fabsf(x);
  float e = __expf(2.0f*ax);
  float t = 1.0f - 2.0f/(e + 1.0f);   // overflow-safe
  return x < 0.0f ? -t : t;
}

__device__ __forceinline__ unsigned short f2bf(float x){    // RNE fp32->bf16
  unsigned u = __builtin_bit_cast(unsigned, x);
  u += 0x7fffu + ((u>>16)&1u);
  return (unsigned short)(u>>16);
}
__device__ __forceinline__ float bf2f(unsigned short h){
  unsigned u = ((unsigned)h)<<16;
  return __builtin_bit_cast(float, u);
}

__device__ __forceinline__ f32x4 mm(short8 a, short8 b, f32x4 c){
  return __builtin_amdgcn_mfma_f32_16x16x32_bf16(a, b, c, 0, 0, 0);
}

// dataflow sync primitives (agent scope, LLC)
__device__ __forceinline__ void wait_eq(unsigned* p, unsigned v){
  while (__hip_atomic_load(p, __ATOMIC_RELAXED, __HIP_MEMORY_SCOPE_AGENT) != v)
    __builtin_amdgcn_s_sleep(1);
}
__device__ __forceinline__ void bump(unsigned* p){
  __hip_atomic_fetch_add(p, 1u, __ATOMIC_RELEASE, __HIP_MEMORY_SCOPE_AGENT);
}
#define ACQ() __builtin_amdgcn_fence(__ATOMIC_ACQUIRE, "agent")

// async stage 131072 bytes global->LDS, linear layout, 512 threads
__device__ __forceinline__ void stage_lds(const void* g, unsigned char* smem, int tid){
  const char* gp = (const char*)g;
  #pragma unroll
  for (int i = 0; i < 16; ++i){
    unsigned o = (unsigned)i*8192u + (unsigned)tid*16u;
    __builtin_amdgcn_global_load_lds(
        (GU32*)(gp + o),
        (LU32*)(smem + (unsigned)i*8192u + (unsigned)(tid & ~63)*16u),
        16, 0, 0);
  }
}

// pack 16 A-fragments (hi & lo bf16) for one wave
__device__ __forceinline__ void apack(const float* __restrict__ W, int u_w, int l15, int hig,
                                      short8* whi, short8* wlo){
  const int m = l15;
  const int row = (m&3)*HID + u_w + (m>>2);
  const float* wp0 = W + row*HID + hig*8;
  #pragma unroll
  for (int kt = 0; kt < 16; ++kt){
    short8 h8, l8;
    #pragma unroll
    for (int j = 0; j < 8; ++j){
      float v = wp0[kt*32 + j];
      unsigned short hb = f2bf(v);
      h8[j] = (short)hb;
      l8[j] = (short)f2bf(v - bf2f(hb));
    }
    whi[kt] = h8; wlo[kt] = l8;
  }
}

__device__ __forceinline__ void ktloop(const unsigned char* smem, const short8* whi, const short8* wlo,
                                       int hig, int l15, f32x4* acc){
  #pragma unroll
  for (int kt = 0; kt < 16; ++kt){
    const unsigned base = (unsigned)((kt*4+hig)*64)*16u;
    #pragma unroll
    for (int nt = 0; nt < 4; ++nt){
      const unsigned eb = base + (unsigned)(nt*16 + l15)*16u;
      short8 bhi = *(const short8*)(smem + eb);
      short8 blo = *(const short8*)(smem + 65536u + eb);
      acc[nt] = mm(whi[kt], bhi, acc[nt]);
      acc[nt] = mm(wlo[kt], bhi, acc[nt]);
      acc[nt] = mm(whi[kt], blo, acc[nt]);
    }
  }
}

// transpose y -> yT; zero ring slot 3 (t=-1 state) of h1,h2; zero flags
__global__ void init_kernel(const float* __restrict__ y, float* __restrict__ ws){
  int idx = blockIdx.x*256 + threadIdx.x;
  if (idx < LSEQ*N_B){
    int t = idx >> 7, n = idx & 127;
    ws[OFF_YT + idx] = y[n*LSEQ + t];
  }
  if (idx < 65536){
    ((unsigned*)(ws + OFF_H1F))[196608 + idx] = 0u;   // slot 3, both bg
    ((unsigned*)(ws + OFF_H2F))[196608 + idx] = 0u;
  }
  if (idx < 8*FSTRIDE) ((unsigned*)(ws + OFF_FLAGS))[idx] = 0u;
}

__launch_bounds__(512)
__global__ void lstm_kernel(
    const float* __restrict__ yT,
    const float* __restrict__ Wih1, const float* __restrict__ Whh1,
    const float* __restrict__ bi1,  const float* __restrict__ bh1,
    const float* __restrict__ Wih2, const float* __restrict__ Whh2,
    const float* __restrict__ bi2,  const float* __restrict__ bh2,
    const float* __restrict__ Wlin, const float* __restrict__ blin,
    unsigned short* __restrict__ h1u, unsigned short* __restrict__ h2u,
    float* __restrict__ out, unsigned* __restrict__ syncp)
{
  __shared__ unsigned char smem[147456];   // 128KB stage + 16KB psum
  const int tid  = threadIdx.x;
  const int lane = tid & 63;
  const int wv   = __builtin_amdgcn_readfirstlane(tid >> 6);
  const int blk  = blockIdx.x;
  const int l15  = lane & 15, hig = lane >> 4;

  if (blk < 32){
    // -------- layer 1: 2bg x 16 blocks, 32 units/block, wave = 4 units --------
    const int bg = blk >> 4, ug = blk & 15;
    const int u_w = ug*32 + wv*4;
    unsigned* flags1 = syncp + bg*FSTRIDE;
    unsigned* rd1    = syncp + (4+bg)*FSTRIDE;
    short8 whi[16], wlo[16];
    apack(Whh1, u_w, l15, hig, whi, wlo);
    float bsum[4], wih[4];
    #pragma unroll
    for (int r = 0; r < 4; ++r){
      int row = r*HID + u_w + hig;
      bsum[r] = bi1[row] + bh1[row];
      wih[r]  = Wih1[row];
    }
    float c1[4] = {0.f,0.f,0.f,0.f};
    const int u_abs = u_w + hig;
    const int ebase = ((u_abs>>5)*4 + ((u_abs>>3)&3))*512 + (u_abs&7);

    #pragma clang loop unroll(disable)
    for (int p = 0; p < LSEQ; ++p){
      if (tid == 0){
        if (p >= 3) wait_eq(rd1 + (p-3), 48u);      // ring slot p&3 free
        if (p >= 1) wait_eq(flags1 + (p-1), 16u);   // h1(p-1) ready
        ACQ();
      }
      __syncthreads();
      stage_lds(h1u + ((unsigned)(((p+3)&3)*2 + bg) << 16), smem, tid);
      float yv[4];
      #pragma unroll
      for (int nt = 0; nt < 4; ++nt) yv[nt] = yT[p*N_B + bg*64 + nt*16 + l15];
      __syncthreads();
      if (tid == 0) bump(rd1 + p);                  // done reading h1(p-1)
      f32x4 acc[4];
      #pragma unroll
      for (int nt = 0; nt < 4; ++nt) acc[nt] = (f32x4){0.f,0.f,0.f,0.f};
      ktloop(smem, whi, wlo, hig, l15, acc);
      unsigned short* hd = h1u + ((unsigned)((p&3)*2 + bg) << 16);
      #pragma unroll
      for (int nt = 0; nt < 4; ++nt){
        float gi = acc[nt][0] + bsum[0] + wih[0]*yv[nt];
        float gf = acc[nt][1] + bsum[1] + wih[1]*yv[nt];
        float gg = acc[nt][2] + bsum[2] + wih[2]*yv[nt];
        float go = acc[nt][3] + bsum[3] + wih[3]*yv[nt];
        float cn = sigm(gf)*c1[nt] + sigm(gi)*tanhf_fast(gg);
        c1[nt] = cn;
        float hn = sigm(go)*tanhf_fast(cn);
        unsigned short hb = f2bf(hn);
        unsigned short lb = f2bf(hn - bf2f(hb));
        int e = ebase + (nt*16 + l15)*8;
        hd[e] = hb; hd[32768 + e] = lb;
      }
      __syncthreads();
      if (tid == 0) bump(flags1 + p);               // h1(p) published
    }
  } else if (blk < 96){
    // -------- layer 2: 2bg x 32 blocks, 16 units/block; mat=wv>>2 picks matrix --------
    const int b2 = blk - 32, bg = b2 >> 5, ub = (b2 & 31)*16;
    unsigned* flags1 = syncp + bg*FSTRIDE;
    unsigned* flags2 = syncp + (2+bg)*FSTRIDE;
    unsigned* rd1    = syncp + (4+bg)*FSTRIDE;
    unsigned* rd2    = syncp + (6+bg)*FSTRIDE;
    const int mt = wv & 3, mat = wv >> 2;
    const int u_w = ub + mt*4;
    short8 whi[16], wlo[16];
    apack(mat ? Whh2 : Wih2, u_w, l15, hig, whi, wlo);
    float bsum[4], c2[4] = {0.f,0.f,0.f,0.f};
    #pragma unroll
    for (int r = 0; r < 4; ++r){
      int row = r*HID + u_w + hig;
      bsum[r] = bi2[row] + bh2[row];
    }
    const int u_abs = u_w + hig;
    const int ebase = ((u_abs>>5)*4 + ((u_abs>>3)&3))*512 + (u_abs&7);

    #pragma clang loop unroll(disable)
    for (int p = 0; p <= LSEQ; ++p){
      const bool act = (p >= 1);
      if (tid == 0){
        if (p >= 4) wait_eq(rd2 + (p-3), 33u);        // h2 ring slot (p+3)&3 free
        if (act){
          wait_eq(flags1 + (p-1), 16u);               // h1(p-1) ready
          if (p >= 2) wait_eq(flags2 + (p-2), 32u);   // h2(p-2) ready
          ACQ();
        }
      }
      __syncthreads();
      if (act){
        f32x4 acc[4];
        #pragma unroll
        for (int nt = 0; nt < 4; ++nt) acc[nt] = (f32x4){0.f,0.f,0.f,0.f};
        // phase A: stage h1(p-1), ih-waves compute
        stage_lds(h1u + ((unsigned)(((p+3)&3)*2 + bg) << 16), smem, tid);
        __syncthreads();
        if (tid == 0) bump(rd1 + p);
        if (mat == 0) ktloop(smem, whi, wlo, hig, l15, acc);
        __syncthreads();
        // phase B: stage h2(p-2), hh-waves compute, dump psum
        stage_lds(h2u + ((unsigned)(((p+2)&3)*2 + bg) << 16), smem, tid);
        __syncthreads();
        if (tid == 0) bump(rd2 + p);
        if (mat == 1){
          ktloop(smem, whi, wlo, hig, l15, acc);
          #pragma unroll
          for (int nt = 0; nt < 4; ++nt)
            *(f32x4*)(smem + PSUM_OFF + (unsigned)((mt*4+nt)*64 + lane)*16u) = acc[nt];
        }
        __syncthreads();
        if (mat == 0){
          unsigned short* hd = h2u + ((unsigned)(((p+3)&3)*2 + bg) << 16);
          #pragma unroll
          for (int nt = 0; nt < 4; ++nt){
            f32x4 ps = *(const f32x4*)(smem + PSUM_OFF + (unsigned)((mt*4+nt)*64 + lane)*16u);
            float gi = acc[nt][0] + ps[0] + bsum[0];
            float gf = acc[nt][1] + ps[1] + bsum[1];
            float gg = acc[nt][2] + ps[2] + bsum[2];
            float go = acc[nt][3] + ps[3] + bsum[3];
            float cn = sigm(gf)*c2[nt] + sigm(gi)*tanhf_fast(gg);
            c2[nt] = cn;
            float hn = sigm(go)*tanhf_fast(cn);
            unsigned short hb = f2bf(hn);
            unsigned short lb = f2bf(hn - bf2f(hb));
            int e = ebase + (nt*16 + l15)*8;
            hd[e] = hb; hd[32768 + e] = lb;
          }
        }
        __syncthreads();
        if (tid == 0) bump(flags2 + (p-1));           // h2(p-1) published
      } else {
        if (tid == 0){ bump(rd1 + p); bump(rd2 + p); }
        __syncthreads();
      }
    }
  } else {
    // -------- output blocks (one per bg): out(t=p-2) = h2(p-2).Wlin + b --------
    const int bg = blk - 96;
    unsigned* flags2 = syncp + (2+bg)*FSTRIDE;
    unsigned* rd2    = syncp + (6+bg)*FSTRIDE;
    float wl[64];
    #pragma unroll
    for (int g8 = 0; g8 < 8; ++g8){
      int kt = wv*2 + (g8>>2), hg = g8 & 3;
      #pragma unroll
      for (int j = 0; j < 8; ++j) wl[g8*8+j] = Wlin[kt*32 + hg*8 + j];
    }
    const float bl = blin[0];
    #pragma clang loop unroll(disable)
    for (int p = 0; p < LSEQ + 2; ++p){
      const bool act = (p >= 2);
      if (tid == 0 && act){
        wait_eq(flags2 + (p-2), 32u);
        ACQ();
      }
      __syncthreads();
      if (act){
        const int t = p - 2;
        const unsigned short* hr = h2u + ((unsigned)(((p+2)&3)*2 + bg) << 16);
        float a = 0.f;
        #pragma unroll
        for (int g8 = 0; g8 < 8; ++g8){
          int kt = wv*2 + (g8>>2), hg = g8 & 3;
          unsigned e = (unsigned)((kt*4+hg)*64 + lane)*8u;
          ushort8 hi8 = *(const ushort8*)(hr + e);
          ushort8 lo8 = *(const ushort8*)(hr + 32768u + e);
          #pragma unroll
          for (int j = 0; j < 8; ++j)
            a += (bf2f(hi8[j]) + bf2f(lo8[j])) * wl[g8*8+j];
        }
        ((float*)smem)[wv*64 + lane] = a;
        __syncthreads();
        if (wv == 0){
          float s = bl;
          #pragma unroll
          for (int w = 0; w < 8; ++w) s += ((float*)smem)[w*64 + lane];
          out[(bg*64 + lane)*LSEQ + t] = s;
        }
      }
      __syncthreads();
      if (tid == 0) bump(rd2 + p);                    // done reading h2(p-2)
    }
  }
}

extern "C" void kernel_launch(void* const* d_in, const int* in_sizes, int n_in,
                              void* d_out, int out_size, void* d_ws, size_t ws_size,
                              hipStream_t stream){
  (void)in_sizes; (void)n_in; (void)out_size; (void)ws_size;
  const float* y    = (const float*)d_in[0];
  const float* Wih1 = (const float*)d_in[1];
  const float* Whh1 = (const float*)d_in[2];
  const float* bi1  = (const float*)d_in[3];
  const float* bh1  = (const float*)d_in[4];
  const float* Wih2 = (const float*)d_in[5];
  const float* Whh2 = (const float*)d_in[6];
  const float* bi2  = (const float*)d_in[7];
  const float* bh2  = (const float*)d_in[8];
  const float* Wlin = (const float*)d_in[9];
  const float* blin = (const float*)d_in[10];
  float* ws  = (float*)d_ws;
  float* out = (float*)d_out;

  hipLaunchKernelGGL(init_kernel, dim3(1024), dim3(256), 0, stream, y, ws);

  const float* yT = ws + OFF_YT;
  unsigned short* h1u = (unsigned short*)(ws + OFF_H1F);
  unsigned short* h2u = (unsigned short*)(ws + OFF_H2F);
  unsigned* syncp = (unsigned*)(ws + OFF_FLAGS);

  void* args[] = { (void*)&yT, (void*)&Wih1, (void*)&Whh1, (void*)&bi1, (void*)&bh1,
                   (void*)&Wih2, (void*)&Whh2, (void*)&bi2, (void*)&bh2,
                   (void*)&Wlin, (void*)&blin, (void*)&h1u, (void*)&h2u,
                   (void*)&out, (void*)&syncp };
  hipLaunchCooperativeKernel((void*)lstm_kernel, dim3(98), dim3(512), args, 0, stream);
}

// Round 4
// 26165.860 us; speedup vs baseline: 6.0490x; 1.0971x over previous
//
#include <hip/hip_runtime.h>

#define N_B 128
#define LSEQ 2048
#define HID 512

// ws float offsets
#define OFF_YT 0
#define OFF_H1F 262144                 // h1 ring: 4 slots x 2 bg x 65536 u16 = 1MB
#define OFF_H2F (OFF_H1F + 262144)     // h2 ring: 1MB
#define OFF_FLAGS (OFF_H2F + 262144)   // 8*2056 u32 = 64KB
#define FSTRIDE 2056

#define PSUM_OFF 131072                // LDS byte offset of psum area

typedef __attribute__((ext_vector_type(8))) short short8;
typedef __attribute__((ext_vector_type(4))) float f32x4;
typedef __attribute__((ext_vector_type(8))) unsigned short ushort8;

typedef __attribute__((address_space(1))) const unsigned int GU32;
typedef __attribute__((address_space(3))) unsigned int LU32;

__device__ __forceinline__ float sigm(float x){ return 1.0f/(1.0f + __expf(-x)); }
__device__ __forceinline__ float tanhf_fast(float x){
  float ax = fabsf(x);
  float e = __expf(2.0f*ax);
  float t = 1.0f - 2.0f/(e + 1.0f);   // overflow-safe
  return x < 0.0f ? -t : t;
}

__device__ __forceinline__ unsigned short f2bf(float x){    // RNE fp32->bf16
  unsigned u = __builtin_bit_cast(unsigned, x);
  u += 0x7fffu + ((u>>16)&1u);
  return (unsigned short)(u>>16);
}
__device__ __forceinline__ float bf2f(unsigned short h){
  unsigned u = ((unsigned)h)<<16;
  return __builtin_bit_cast(float, u);
}

__device__ __forceinline__ f32x4 mm(short8 a, short8 b, f32x4 c){
  return __builtin_amdgcn_mfma_f32_16x16x32_bf16(a, b, c, 0, 0, 0);
}

// dataflow sync primitives (agent scope, LLC)
__device__ __forceinline__ void wait_eq(unsigned* p, unsigned v){
  while (__hip_atomic_load(p, __ATOMIC_RELAXED, __HIP_MEMORY_SCOPE_AGENT) != v)
    __builtin_amdgcn_s_sleep(1);
}
__device__ __forceinline__ void bump_rel(unsigned* p){      // publish: needs release (wbl2)
  __hip_atomic_fetch_add(p, 1u, __ATOMIC_RELEASE, __HIP_MEMORY_SCOPE_AGENT);
}
__device__ __forceinline__ void bump_rlx(unsigned* p){      // read-done: syncthreads already drained vmcnt
  __hip_atomic_fetch_add(p, 1u, __ATOMIC_RELAXED, __HIP_MEMORY_SCOPE_AGENT);
}
#define ACQ() __builtin_amdgcn_fence(__ATOMIC_ACQUIRE, "agent")

// async stage 65536 bytes (one plane) global -> LDS, linear layout, 512 threads
__device__ __forceinline__ void stage64(const void* g, unsigned char* smem, int tid){
  const char* gp = (const char*)g;
  #pragma unroll
  for (int i = 0; i < 8; ++i){
    unsigned o = (unsigned)i*8192u + (unsigned)tid*16u;
    __builtin_amdgcn_global_load_lds(
        (GU32*)(gp + o),
        (LU32*)(smem + (unsigned)i*8192u + (unsigned)(tid & ~63)*16u),
        16, 0, 0);
  }
}

// pack 16 A-fragments (hi & lo bf16) for one wave
__device__ __forceinline__ void apack(const float* __restrict__ W, int u_w, int l15, int hig,
                                      short8* whi, short8* wlo){
  const int m = l15;
  const int row = (m&3)*HID + u_w + (m>>2);
  const float* wp0 = W + row*HID + hig*8;
  #pragma unroll
  for (int kt = 0; kt < 16; ++kt){
    short8 h8, l8;
    #pragma unroll
    for (int j = 0; j < 8; ++j){
      float v = wp0[kt*32 + j];
      unsigned short hb = f2bf(v);
      h8[j] = (short)hb;
      l8[j] = (short)f2bf(v - bf2f(hb));
    }
    whi[kt] = h8; wlo[kt] = l8;
  }
}

// hi-plane products: Ahi*Bhi + Alo*Bhi   (128 MFMA)
__device__ __forceinline__ void kt_hi(const unsigned char* buf, const short8* whi, const short8* wlo,
                                      int hig, int l15, f32x4* acc){
  #pragma unroll
  for (int kt = 0; kt < 16; ++kt){
    const unsigned base = (unsigned)((kt*4+hig)*64)*16u;
    #pragma unroll
    for (int nt = 0; nt < 4; ++nt){
      short8 b = *(const short8*)(buf + base + (unsigned)(nt*16 + l15)*16u);
      acc[nt] = mm(whi[kt], b, acc[nt]);
      acc[nt] = mm(wlo[kt], b, acc[nt]);
    }
  }
}
// lo-plane product: Ahi*Blo   (64 MFMA)
__device__ __forceinline__ void kt_lo(const unsigned char* buf, const short8* whi,
                                      int hig, int l15, f32x4* acc){
  #pragma unroll
  for (int kt = 0; kt < 16; ++kt){
    const unsigned base = (unsigned)((kt*4+hig)*64)*16u;
    #pragma unroll
    for (int nt = 0; nt < 4; ++nt){
      short8 b = *(const short8*)(buf + base + (unsigned)(nt*16 + l15)*16u);
      acc[nt] = mm(whi[kt], b, acc[nt]);
    }
  }
}

// transpose y -> yT; zero ring slot 3 (t=-1 state) of h1,h2; zero flags
__global__ void init_kernel(const float* __restrict__ y, float* __restrict__ ws){
  int idx = blockIdx.x*256 + threadIdx.x;
  if (idx < LSEQ*N_B){
    int t = idx >> 7, n = idx & 127;
    ws[OFF_YT + idx] = y[n*LSEQ + t];
  }
  if (idx < 65536){
    ((unsigned*)(ws + OFF_H1F))[196608 + idx] = 0u;   // slot 3, both bg
    ((unsigned*)(ws + OFF_H2F))[196608 + idx] = 0u;
  }
  if (idx < 8*FSTRIDE) ((unsigned*)(ws + OFF_FLAGS))[idx] = 0u;
}

__launch_bounds__(512)
__global__ void lstm_kernel(
    const float* __restrict__ yT,
    const float* __restrict__ Wih1, const float* __restrict__ Whh1,
    const float* __restrict__ bi1,  const float* __restrict__ bh1,
    const float* __restrict__ Wih2, const float* __restrict__ Whh2,
    const float* __restrict__ bi2,  const float* __restrict__ bh2,
    const float* __restrict__ Wlin, const float* __restrict__ blin,
    unsigned short* __restrict__ h1u, unsigned short* __restrict__ h2u,
    float* __restrict__ out, unsigned* __restrict__ syncp)
{
  __shared__ unsigned char smem[147456];   // 2x64KB ping-pong + 16KB psum
  unsigned char* buf0 = smem;
  unsigned char* buf1 = smem + 65536;
  const int tid  = threadIdx.x;
  const int lane = tid & 63;
  const int wv   = __builtin_amdgcn_readfirstlane(tid >> 6);
  const int blk  = blockIdx.x;
  const int l15  = lane & 15, hig = lane >> 4;

  if (blk < 32){
    // -------- layer 1: 2bg x 16 blocks, 32 units/block, wave = 4 units --------
    const int bg = blk >> 4, ug = blk & 15;
    const int u_w = ug*32 + wv*4;
    unsigned* flags1 = syncp + bg*FSTRIDE;
    unsigned* rd1    = syncp + (4+bg)*FSTRIDE;
    short8 whi[16], wlo[16];
    apack(Whh1, u_w, l15, hig, whi, wlo);
    float bsum[4], wih[4];
    #pragma unroll
    for (int r = 0; r < 4; ++r){
      int row = r*HID + u_w + hig;
      bsum[r] = bi1[row] + bh1[row];
      wih[r]  = Wih1[row];
    }
    float c1[4] = {0.f,0.f,0.f,0.f};
    const int u_abs = u_w + hig;
    const int ebase = ((u_abs>>5)*4 + ((u_abs>>3)&3))*512 + (u_abs&7);

    #pragma clang loop unroll(disable)
    for (int p = 0; p < LSEQ; ++p){
      if (tid == 0){
        if (p >= 3) wait_eq(rd1 + (p-3), 48u);      // ring slot p&3 free
        if (p >= 1) wait_eq(flags1 + (p-1), 16u);   // h1(p-1) ready
        ACQ();
      }
      __syncthreads();                                            // B0
      const unsigned short* src = h1u + ((unsigned)(((p+3)&3)*2 + bg) << 16);
      stage64(src, buf0, tid);
      float yv[4];
      #pragma unroll
      for (int nt = 0; nt < 4; ++nt) yv[nt] = yT[p*N_B + bg*64 + nt*16 + l15];
      __syncthreads();                                            // B1: buf0 ready
      stage64(src + 32768, buf1, tid);
      f32x4 acc[4];
      #pragma unroll
      for (int nt = 0; nt < 4; ++nt) acc[nt] = (f32x4){0.f,0.f,0.f,0.f};
      kt_hi(buf0, whi, wlo, hig, l15, acc);
      __syncthreads();                                            // B2: buf1 ready, h1 reads done
      if (tid == 0) bump_rlx(rd1 + p);
      kt_lo(buf1, whi, hig, l15, acc);
      unsigned short* hd = h1u + ((unsigned)((p&3)*2 + bg) << 16);
      #pragma unroll
      for (int nt = 0; nt < 4; ++nt){
        float gi = acc[nt][0] + bsum[0] + wih[0]*yv[nt];
        float gf = acc[nt][1] + bsum[1] + wih[1]*yv[nt];
        float gg = acc[nt][2] + bsum[2] + wih[2]*yv[nt];
        float go = acc[nt][3] + bsum[3] + wih[3]*yv[nt];
        float cn = sigm(gf)*c1[nt] + sigm(gi)*tanhf_fast(gg);
        c1[nt] = cn;
        float hn = sigm(go)*tanhf_fast(cn);
        unsigned short hb = f2bf(hn);
        unsigned short lb = f2bf(hn - bf2f(hb));
        int e = ebase + (nt*16 + l15)*8;
        __builtin_nontemporal_store(hb, hd + e);
        __builtin_nontemporal_store(lb, hd + 32768 + e);
      }
      __syncthreads();                                            // B3: stores drained
      if (tid == 0) bump_rel(flags1 + p);                         // h1(p) published
    }
  } else if (blk < 96){
    // -------- layer 2: 2bg x 32 blocks, 16 units/block; mat=wv>>2 picks matrix --------
    const int b2 = blk - 32, bg = b2 >> 5, ub = (b2 & 31)*16;
    unsigned* flags1 = syncp + bg*FSTRIDE;
    unsigned* flags2 = syncp + (2+bg)*FSTRIDE;
    unsigned* rd1    = syncp + (4+bg)*FSTRIDE;
    unsigned* rd2    = syncp + (6+bg)*FSTRIDE;
    const int mt = wv & 3, mat = wv >> 2;
    const int u_w = ub + mt*4;
    short8 whi[16], wlo[16];
    apack(mat ? Whh2 : Wih2, u_w, l15, hig, whi, wlo);
    float bsum[4], c2[4] = {0.f,0.f,0.f,0.f};
    #pragma unroll
    for (int r = 0; r < 4; ++r){
      int row = r*HID + u_w + hig;
      bsum[r] = bi2[row] + bh2[row];
    }
    const int u_abs = u_w + hig;
    const int ebase = ((u_abs>>5)*4 + ((u_abs>>3)&3))*512 + (u_abs&7);

    #pragma clang loop unroll(disable)
    for (int p = 0; p <= LSEQ; ++p){
      const bool act = (p >= 1);
      // two parallel waiters: tid0 gates h1 phase, tid256 gates h2 phase (overlapped)
      if (tid == 0 && act){ wait_eq(flags1 + (p-1), 16u); ACQ(); }
      if (tid == 256){
        if (p >= 4) wait_eq(rd2 + (p-3), 33u);        // h2 write slot free
        if (p >= 2) wait_eq(flags2 + (p-2), 32u);     // h2(p-2) ready
        ACQ();
      }
      __syncthreads();                                            // B0
      if (act){
        const unsigned short* src1 = h1u + ((unsigned)(((p+3)&3)*2 + bg) << 16);
        stage64(src1, buf0, tid);
        __syncthreads();                                          // B1: buf0=h1hi
        stage64(src1 + 32768, buf1, tid);
        f32x4 acc[4];
        #pragma unroll
        for (int nt = 0; nt < 4; ++nt) acc[nt] = (f32x4){0.f,0.f,0.f,0.f};
        if (mat == 0) kt_hi(buf0, whi, wlo, hig, l15, acc);
        __syncthreads();                                          // B2: buf1=h1lo; h1 reads done
        if (tid == 0) bump_rlx(rd1 + p);
        const unsigned short* src2 = h2u + ((unsigned)(((p+2)&3)*2 + bg) << 16);
        stage64(src2, buf0, tid);
        if (mat == 0) kt_lo(buf1, whi, hig, l15, acc);
        __syncthreads();                                          // B3: buf0=h2hi
        stage64(src2 + 32768, buf1, tid);
        if (mat == 1) kt_hi(buf0, whi, wlo, hig, l15, acc);
        __syncthreads();                                          // B4: buf1=h2lo; h2 reads done
        if (tid == 0) bump_rlx(rd2 + p);
        if (mat == 1){
          kt_lo(buf1, whi, hig, l15, acc);
          #pragma unroll
          for (int nt = 0; nt < 4; ++nt)
            *(f32x4*)(smem + PSUM_OFF + (unsigned)((mt*4+nt)*64 + lane)*16u) = acc[nt];
        }
        __syncthreads();                                          // B5: psum ready
        if (mat == 0){
          unsigned short* hd = h2u + ((unsigned)(((p+3)&3)*2 + bg) << 16);
          #pragma unroll
          for (int nt = 0; nt < 4; ++nt){
            f32x4 ps = *(const f32x4*)(smem + PSUM_OFF + (unsigned)((mt*4+nt)*64 + lane)*16u);
            float gi = acc[nt][0] + ps[0] + bsum[0];
            float gf = acc[nt][1] + ps[1] + bsum[1];
            float gg = acc[nt][2] + ps[2] + bsum[2];
            float go = acc[nt][3] + ps[3] + bsum[3];
            float cn = sigm(gf)*c2[nt] + sigm(gi)*tanhf_fast(gg);
            c2[nt] = cn;
            float hn = sigm(go)*tanhf_fast(cn);
            unsigned short hb = f2bf(hn);
            unsigned short lb = f2bf(hn - bf2f(hb));
            int e = ebase + (nt*16 + l15)*8;
            __builtin_nontemporal_store(hb, hd + e);
            __builtin_nontemporal_store(lb, hd + 32768 + e);
          }
        }
        __syncthreads();                                          // B6: stores drained
        if (tid == 0) bump_rel(flags2 + (p-1));                   // h2(p-1) published
      } else {
        if (tid == 0){ bump_rlx(rd1 + p); bump_rlx(rd2 + p); }
        __syncthreads();
      }
    }
  } else {
    // -------- output blocks (one per bg): out(t=p-2) = h2(p-2).Wlin + b --------
    const int bg = blk - 96;
    unsigned* flags2 = syncp + (2+bg)*FSTRIDE;
    unsigned* rd2    = syncp + (6+bg)*FSTRIDE;
    float wl[64];
    #pragma unroll
    for (int g8 = 0; g8 < 8; ++g8){
      int kt = wv*2 + (g8>>2), hg = g8 & 3;
      #pragma unroll
      for (int j = 0; j < 8; ++j) wl[g8*8+j] = Wlin[kt*32 + hg*8 + j];
    }
    const float bl = blin[0];
    #pragma clang loop unroll(disable)
    for (int p = 0; p < LSEQ + 2; ++p){
      const bool act = (p >= 2);
      if (tid == 0 && act){
        wait_eq(flags2 + (p-2), 32u);
        ACQ();
      }
      __syncthreads();
      if (act){
        const int t = p - 2;
        const unsigned short* hr = h2u + ((unsigned)(((p+2)&3)*2 + bg) << 16);
        float a = 0.f;
        #pragma unroll
        for (int g8 = 0; g8 < 8; ++g8){
          int kt = wv*2 + (g8>>2), hg = g8 & 3;
          unsigned e = (unsigned)((kt*4+hg)*64 + lane)*8u;
          ushort8 hi8 = *(const ushort8*)(hr + e);
          ushort8 lo8 = *(const ushort8*)(hr + 32768u + e);
          #pragma unroll
          for (int j = 0; j < 8; ++j)
            a += (bf2f(hi8[j]) + bf2f(lo8[j])) * wl[g8*8+j];
        }
        ((float*)smem)[wv*64 + lane] = a;
        __syncthreads();
        if (wv == 0){
          float s = bl;
          #pragma unroll
          for (int w = 0; w < 8; ++w) s += ((float*)smem)[w*64 + lane];
          __builtin_nontemporal_store(s, out + (bg*64 + lane)*LSEQ + t);
        }
      }
      __syncthreads();
      if (tid == 0) bump_rlx(rd2 + p);                // done reading h2(p-2)
    }
  }
}

extern "C" void kernel_launch(void* const* d_in, const int* in_sizes, int n_in,
                              void* d_out, int out_size, void* d_ws, size_t ws_size,
                              hipStream_t stream){
  (void)in_sizes; (void)n_in; (void)out_size; (void)ws_size;
  const float* y    = (const float*)d_in[0];
  const float* Wih1 = (const float*)d_in[1];
  const float* Whh1 = (const float*)d_in[2];
  const float* bi1  = (const float*)d_in[3];
  const float* bh1  = (const float*)d_in[4];
  const float* Wih2 = (const float*)d_in[5];
  const float* Whh2 = (const float*)d_in[6];
  const float* bi2  = (const float*)d_in[7];
  const float* bh2  = (const float*)d_in[8];
  const float* Wlin = (const float*)d_in[9];
  const float* blin = (const float*)d_in[10];
  float* ws  = (float*)d_ws;
  float* out = (float*)d_out;

  hipLaunchKernelGGL(init_kernel, dim3(1024), dim3(256), 0, stream, y, ws);

  const float* yT = ws + OFF_YT;
  unsigned short* h1u = (unsigned short*)(ws + OFF_H1F);
  unsigned short* h2u = (unsigned short*)(ws + OFF_H2F);
  unsigned* syncp = (unsigned*)(ws + OFF_FLAGS);

  void* args[] = { (void*)&yT, (void*)&Wih1, (void*)&Whh1, (void*)&bi1, (void*)&bh1,
                   (void*)&Wih2, (void*)&Whh2, (void*)&bi2, (void*)&bh2,
                   (void*)&Wlin, (void*)&blin, (void*)&h1u, (void*)&h2u,
                   (void*)&out, (void*)&syncp };
  hipLaunchCooperativeKernel((void*)lstm_kernel, dim3(98), dim3(512), args, 0, stream);
}

// Round 5
// 24445.741 us; speedup vs baseline: 6.4747x; 1.0704x over previous
//
#include <hip/hip_runtime.h>

#define N_B 128
#define LSEQ 2048
#define HID 512

// ws float offsets
#define OFF_YT 0
#define OFF_H1F 262144     // h1 ring: 4 slots x 2 bg x 65536 u16 = 262144 floats
#define OFF_H2F 524288     // h2 ring: same
#define OFF_FLAGS 786432   // u32 one-shot flag area

// flag u32 offsets within flag area
#define F1_OFF 0                        // [t][bg][16]
#define F2_OFF (2052*2*16)              // [t][bg][32]
#define FO_OFF (F2_OFF + 2052*2*32)     // [t][bg]
#define FLAG_WORDS (FO_OFF + 2052*2)

#define PSUM_OFF 131072                 // LDS byte offset of psum area

typedef __attribute__((ext_vector_type(8))) short short8;
typedef __attribute__((ext_vector_type(4))) float f32x4;
typedef __attribute__((ext_vector_type(8))) unsigned short ushort8;

typedef __attribute__((address_space(1))) const unsigned int GU32;
typedef __attribute__((address_space(3))) unsigned int LU32;

__device__ __forceinline__ float sigm(float x){ return 1.0f/(1.0f + __expf(-x)); }
__device__ __forceinline__ float tanhf_fast(float x){
  float ax = fabsf(x);
  float e = __expf(2.0f*ax);
  float t = 1.0f - 2.0f/(e + 1.0f);   // overflow-safe
  return x < 0.0f ? -t : t;
}

__device__ __forceinline__ unsigned short f2bf(float x){    // RNE fp32->bf16
  unsigned u = __builtin_bit_cast(unsigned, x);
  u += 0x7fffu + ((u>>16)&1u);
  return (unsigned short)(u>>16);
}
__device__ __forceinline__ float bf2f(unsigned short h){
  unsigned u = ((unsigned)h)<<16;
  return __builtin_bit_cast(float, u);
}

__device__ __forceinline__ f32x4 mm(short8 a, short8 b, f32x4 c){
  return __builtin_amdgcn_mfma_f32_16x16x32_bf16(a, b, c, 0, 0, 0);
}

// ---- fence-free dataflow primitives ----
// one-shot flag: producer single relaxed agent store; consumer polls own word.
__device__ __forceinline__ void pollw(unsigned* w){
  while (__hip_atomic_load(w, __ATOMIC_RELAXED, __HIP_MEMORY_SCOPE_AGENT) == 0u)
    __builtin_amdgcn_s_sleep(1);
}
__device__ __forceinline__ void setf(unsigned* w){
  __hip_atomic_store(w, 1u, __ATOMIC_RELAXED, __HIP_MEMORY_SCOPE_AGENT);
}
// device-coherent 2B store: write-through to LLC (never dirty in L2)
__device__ __forceinline__ void st16cc(unsigned short* p, unsigned short v){
  asm volatile("global_store_short %0, %1, off sc0 sc1"
               :: "v"(p), "v"((unsigned)v) : "memory");
}
#define DRAIN() asm volatile("s_waitcnt vmcnt(0)" ::: "memory")

// async stage 65536 bytes (one plane) global -> LDS, linear; sc0|sc1 (0x11)
// bypasses L1/L2 so ring-slot reuse never reads stale lines.
__device__ __forceinline__ void stage64(const void* g, unsigned char* smem, int tid){
  const char* gp = (const char*)g;
  #pragma unroll
  for (int i = 0; i < 8; ++i){
    unsigned o = (unsigned)i*8192u + (unsigned)tid*16u;
    __builtin_amdgcn_global_load_lds(
        (GU32*)(gp + o),
        (LU32*)(smem + (unsigned)i*8192u + (unsigned)(tid & ~63)*16u),
        16, 0, 0x11);
  }
}

// pack 16 A-fragments (hi & lo bf16) for one wave
__device__ __forceinline__ void apack(const float* __restrict__ W, int u_w, int l15, int hig,
                                      short8* whi, short8* wlo){
  const int m = l15;
  const int row = (m&3)*HID + u_w + (m>>2);
  const float* wp0 = W + row*HID + hig*8;
  #pragma unroll
  for (int kt = 0; kt < 16; ++kt){
    short8 h8, l8;
    #pragma unroll
    for (int j = 0; j < 8; ++j){
      float v = wp0[kt*32 + j];
      unsigned short hb = f2bf(v);
      h8[j] = (short)hb;
      l8[j] = (short)f2bf(v - bf2f(hb));
    }
    whi[kt] = h8; wlo[kt] = l8;
  }
}

// hi-plane products: Ahi*Bhi + Alo*Bhi   (128 MFMA)
__device__ __forceinline__ void kt_hi(const unsigned char* buf, const short8* whi, const short8* wlo,
                                      int hig, int l15, f32x4* acc){
  #pragma unroll
  for (int kt = 0; kt < 16; ++kt){
    const unsigned base = (unsigned)((kt*4+hig)*64)*16u;
    #pragma unroll
    for (int nt = 0; nt < 4; ++nt){
      short8 b = *(const short8*)(buf + base + (unsigned)(nt*16 + l15)*16u);
      acc[nt] = mm(whi[kt], b, acc[nt]);
      acc[nt] = mm(wlo[kt], b, acc[nt]);
    }
  }
}
// lo-plane product: Ahi*Blo   (64 MFMA)
__device__ __forceinline__ void kt_lo(const unsigned char* buf, const short8* whi,
                                      int hig, int l15, f32x4* acc){
  #pragma unroll
  for (int kt = 0; kt < 16; ++kt){
    const unsigned base = (unsigned)((kt*4+hig)*64)*16u;
    #pragma unroll
    for (int nt = 0; nt < 4; ++nt){
      short8 b = *(const short8*)(buf + base + (unsigned)(nt*16 + l15)*16u);
      acc[nt] = mm(whi[kt], b, acc[nt]);
    }
  }
}

// transpose y -> yT; zero ring slot 3 (t=-1 state) of h1,h2
__global__ void init_kernel(const float* __restrict__ y, float* __restrict__ ws){
  int idx = blockIdx.x*256 + threadIdx.x;
  if (idx < LSEQ*N_B){
    int t = idx >> 7, n = idx & 127;
    ws[OFF_YT + idx] = y[n*LSEQ + t];
  }
  if (idx < 65536){
    ((unsigned*)(ws + OFF_H1F))[196608 + idx] = 0u;   // slot 3, both bg
    ((unsigned*)(ws + OFF_H2F))[196608 + idx] = 0u;
  }
}

__launch_bounds__(512)
__global__ void lstm_kernel(
    const float* __restrict__ yT,
    const float* __restrict__ Wih1, const float* __restrict__ Whh1,
    const float* __restrict__ bi1,  const float* __restrict__ bh1,
    const float* __restrict__ Wih2, const float* __restrict__ Whh2,
    const float* __restrict__ bi2,  const float* __restrict__ bh2,
    const float* __restrict__ Wlin, const float* __restrict__ blin,
    unsigned short* __restrict__ h1u, unsigned short* __restrict__ h2u,
    float* __restrict__ out, unsigned* __restrict__ flags)
{
  __shared__ unsigned char smem[147456];   // 2x64KB ping-pong + 16KB psum
  unsigned char* buf0 = smem;
  unsigned char* buf1 = smem + 65536;
  const int tid  = threadIdx.x;
  const int lane = tid & 63;
  const int wv   = __builtin_amdgcn_readfirstlane(tid >> 6);
  const int blk  = blockIdx.x;
  const int l15  = lane & 15, hig = lane >> 4;
  unsigned* F1 = flags + F1_OFF;
  unsigned* F2 = flags + F2_OFF;
  unsigned* FO = flags + FO_OFF;

  if (blk < 32){
    // -------- layer 1: 2bg x 16 blocks, 32 units/block, wave = 4 units --------
    const int bg = blk >> 4, ug = blk & 15;
    const int u_w = ug*32 + wv*4;
    short8 whi[16], wlo[16];
    apack(Whh1, u_w, l15, hig, whi, wlo);
    float bsum[4], wih[4];
    #pragma unroll
    for (int r = 0; r < 4; ++r){
      int row = r*HID + u_w + hig;
      bsum[r] = bi1[row] + bh1[row];
      wih[r]  = Wih1[row];
    }
    float c1[4] = {0.f,0.f,0.f,0.f};
    const int u_abs = u_w + hig;
    const int ebase = ((u_abs>>5)*4 + ((u_abs>>3)&3))*512 + (u_abs&7);

    #pragma clang loop unroll(disable)
    for (int t = 0; t < LSEQ; ++t){
      // parallel waits: F1[t-1] (self-recurrence), F2[t-4] (h1 slot reuse)
      if (t >= 1 && tid < 16)               pollw(F1 + ((t-1)*2+bg)*16 + tid);
      if (t >= 4 && tid >= 64 && tid < 96)  pollw(F2 + ((t-4)*2+bg)*32 + (tid-64));
      __syncthreads();                                            // B0
      const unsigned short* src = h1u + ((unsigned)(((t+3)&3)*2 + bg) << 16);
      stage64(src, buf0, tid);
      float yv[4];
      #pragma unroll
      for (int nt = 0; nt < 4; ++nt) yv[nt] = yT[t*N_B + bg*64 + nt*16 + l15];
      __syncthreads();                                            // B1: buf0=hi
      stage64(src + 32768, buf1, tid);
      f32x4 acc[4];
      #pragma unroll
      for (int nt = 0; nt < 4; ++nt) acc[nt] = (f32x4){0.f,0.f,0.f,0.f};
      kt_hi(buf0, whi, wlo, hig, l15, acc);
      __syncthreads();                                            // B2: buf1=lo
      kt_lo(buf1, whi, hig, l15, acc);
      unsigned short* hd = h1u + ((unsigned)((t&3)*2 + bg) << 16);
      #pragma unroll
      for (int nt = 0; nt < 4; ++nt){
        float gi = acc[nt][0] + bsum[0] + wih[0]*yv[nt];
        float gf = acc[nt][1] + bsum[1] + wih[1]*yv[nt];
        float gg = acc[nt][2] + bsum[2] + wih[2]*yv[nt];
        float go = acc[nt][3] + bsum[3] + wih[3]*yv[nt];
        float cn = sigm(gf)*c1[nt] + sigm(gi)*tanhf_fast(gg);
        c1[nt] = cn;
        float hn = sigm(go)*tanhf_fast(cn);
        unsigned short hb = f2bf(hn);
        unsigned short lb = f2bf(hn - bf2f(hb));
        int e = ebase + (nt*16 + l15)*8;
        st16cc(hd + e, hb);
        st16cc(hd + 32768 + e, lb);
      }
      DRAIN();                                                    // stores at LLC
      __syncthreads();                                            // B3
      if (tid == 0) setf(F1 + (t*2+bg)*16 + ug);                  // publish h1(t)
    }
  } else if (blk < 96){
    // -------- layer 2: 2bg x 32 blocks, 16 units/block; mat=wv>>2 picks matrix --------
    const int b2 = blk - 32, bg = b2 >> 5, j32 = b2 & 31, ub = j32*16;
    const int mt = wv & 3, mat = wv >> 2;
    const int u_w = ub + mt*4;
    short8 whi[16], wlo[16];
    apack(mat ? Whh2 : Wih2, u_w, l15, hig, whi, wlo);
    float bsum[4], c2[4] = {0.f,0.f,0.f,0.f};
    #pragma unroll
    for (int r = 0; r < 4; ++r){
      int row = r*HID + u_w + hig;
      bsum[r] = bi2[row] + bh2[row];
    }
    const int u_abs = u_w + hig;
    const int ebase = ((u_abs>>5)*4 + ((u_abs>>3)&3))*512 + (u_abs&7);

    #pragma clang loop unroll(disable)
    for (int t = 0; t < LSEQ; ++t){
      // waits: F2[t-1] (peers done h2(t-1)), FO[t-4] (h2 slot reuse). F1[t] later.
      if (t >= 1 && tid < 32)  pollw(F2 + ((t-1)*2+bg)*32 + tid);
      if (t >= 4 && tid == 128) pollw(FO + (t-4)*2 + bg);
      __syncthreads();                                            // B0
      f32x4 acc[4];
      #pragma unroll
      for (int nt = 0; nt < 4; ++nt) acc[nt] = (f32x4){0.f,0.f,0.f,0.f};
      // phase B first: h2(t-1) (self-produced, ready now)
      const unsigned short* s2 = h2u + ((unsigned)(((t+3)&3)*2 + bg) << 16);
      stage64(s2, buf0, tid);
      __syncthreads();                                            // B1: buf0=h2hi
      stage64(s2 + 32768, buf1, tid);
      if (mat == 1) kt_hi(buf0, whi, wlo, hig, l15, acc);
      __syncthreads();                                            // B2: buf1=h2lo
      if (tid < 16) pollw(F1 + (t*2+bg)*16 + tid);                // h1(t) ready? (overlaps kt_lo)
      if (mat == 1) kt_lo(buf1, whi, hig, l15, acc);
      __syncthreads();                                            // B3: buf0/1 free, F1 seen
      // phase A: h1(t)
      const unsigned short* s1 = h1u + ((unsigned)((t&3)*2 + bg) << 16);
      stage64(s1, buf0, tid);
      __syncthreads();                                            // B4: buf0=h1hi
      stage64(s1 + 32768, buf1, tid);
      if (mat == 0) kt_hi(buf0, whi, wlo, hig, l15, acc);
      if (mat == 1){
        #pragma unroll
        for (int nt = 0; nt < 4; ++nt)
          *(f32x4*)(smem + PSUM_OFF + (unsigned)((mt*4+nt)*64 + lane)*16u) = acc[nt];
      }
      __syncthreads();                                            // B5: buf1=h1lo, psum ready
      if (mat == 0){
        kt_lo(buf1, whi, hig, l15, acc);
        unsigned short* hd = h2u + ((unsigned)((t&3)*2 + bg) << 16);
        #pragma unroll
        for (int nt = 0; nt < 4; ++nt){
          f32x4 ps = *(const f32x4*)(smem + PSUM_OFF + (unsigned)((mt*4+nt)*64 + lane)*16u);
          float gi = acc[nt][0] + ps[0] + bsum[0];
          float gf = acc[nt][1] + ps[1] + bsum[1];
          float gg = acc[nt][2] + ps[2] + bsum[2];
          float go = acc[nt][3] + ps[3] + bsum[3];
          float cn = sigm(gf)*c2[nt] + sigm(gi)*tanhf_fast(gg);
          c2[nt] = cn;
          float hn = sigm(go)*tanhf_fast(cn);
          unsigned short hb = f2bf(hn);
          unsigned short lb = f2bf(hn - bf2f(hb));
          int e = ebase + (nt*16 + l15)*8;
          st16cc(hd + e, hb);
          st16cc(hd + 32768 + e, lb);
        }
      }
      DRAIN();
      __syncthreads();                                            // B6
      if (tid == 0) setf(F2 + (t*2+bg)*32 + j32);                 // publish h2(t)
    }
  } else {
    // -------- output blocks (one per bg): out(t) = h2(t).Wlin + b --------
    const int bg = blk - 96;
    float wl[64];
    #pragma unroll
    for (int g = 0; g < 8; ++g)
      #pragma unroll
      for (int j = 0; j < 8; ++j) wl[g*8+j] = Wlin[wv*64 + g*8 + j];
    const float bl = blin[0];

    #pragma clang loop unroll(disable)
    for (int t = 0; t < LSEQ; ++t){
      if (tid < 32) pollw(F2 + (t*2+bg)*32 + tid);
      __syncthreads();                                            // B0
      const unsigned short* hr = h2u + ((unsigned)((t&3)*2 + bg) << 16);
      stage64(hr, buf0, tid);
      stage64(hr + 32768, buf1, tid);
      __syncthreads();                                            // B1: staged
      if (tid == 0) setf(FO + t*2 + bg);                          // done reading h2(t) from global
      float a = 0.f;
      #pragma unroll
      for (int g = 0; g < 8; ++g){
        unsigned idx = ((unsigned)(wv*8 + g)*512u + (unsigned)lane*8u)*2u;
        ushort8 hi8 = *(const ushort8*)(buf0 + idx);
        ushort8 lo8 = *(const ushort8*)(buf1 + idx);
        #pragma unroll
        for (int j = 0; j < 8; ++j)
          a += (bf2f(hi8[j]) + bf2f(lo8[j])) * wl[g*8+j];
      }
      ((float*)(smem + PSUM_OFF))[wv*64 + lane] = a;
      __syncthreads();                                            // B2: psum
      if (wv == 0){
        float s = bl;
        #pragma unroll
        for (int w = 0; w < 8; ++w) s += ((float*)(smem + PSUM_OFF))[w*64 + lane];
        out[(bg*64 + lane)*LSEQ + t] = s;
      }
    }
  }
}

extern "C" void kernel_launch(void* const* d_in, const int* in_sizes, int n_in,
                              void* d_out, int out_size, void* d_ws, size_t ws_size,
                              hipStream_t stream){
  (void)in_sizes; (void)n_in; (void)out_size; (void)ws_size;
  const float* y    = (const float*)d_in[0];
  const float* Wih1 = (const float*)d_in[1];
  const float* Whh1 = (const float*)d_in[2];
  const float* bi1  = (const float*)d_in[3];
  const float* bh1  = (const float*)d_in[4];
  const float* Wih2 = (const float*)d_in[5];
  const float* Whh2 = (const float*)d_in[6];
  const float* bi2  = (const float*)d_in[7];
  const float* bh2  = (const float*)d_in[8];
  const float* Wlin = (const float*)d_in[9];
  const float* blin = (const float*)d_in[10];
  float* ws  = (float*)d_ws;
  float* out = (float*)d_out;

  unsigned* flags = (unsigned*)(ws + OFF_FLAGS);
  hipMemsetAsync(flags, 0, (size_t)FLAG_WORDS*4u, stream);
  hipLaunchKernelGGL(init_kernel, dim3(1024), dim3(256), 0, stream, y, ws);

  const float* yT = ws + OFF_YT;
  unsigned short* h1u = (unsigned short*)(ws + OFF_H1F);
  unsigned short* h2u = (unsigned short*)(ws + OFF_H2F);

  void* args[] = { (void*)&yT, (void*)&Wih1, (void*)&Whh1, (void*)&bi1, (void*)&bh1,
                   (void*)&Wih2, (void*)&Whh2, (void*)&bi2, (void*)&bh2,
                   (void*)&Wlin, (void*)&blin, (void*)&h1u, (void*)&h2u,
                   (void*)&out, (void*)&flags };
  hipLaunchCooperativeKernel((void*)lstm_kernel, dim3(98), dim3(512), args, 0, stream);
}